// Round 6
// baseline (550.746 us; speedup 1.0000x reference)
//
#include <hip/hip_runtime.h>

// ---------- bf16 helpers ----------
__device__ __forceinline__ float bf2f(unsigned short u){
    union { unsigned int i; float f; } v; v.i = ((unsigned int)u) << 16; return v.f;
}
__device__ __forceinline__ unsigned short f2bf(float f){
    union { unsigned int i; float f; } v; v.f = f;
    unsigned int i = v.i;
    unsigned int r = i + 0x7FFFu + ((i >> 16) & 1u);   // round-nearest-even
    return (unsigned short)(r >> 16);
}
__device__ __forceinline__ float sigm(float x){ return 1.0f / (1.0f + __expf(-x)); }

// flag-dispatched scalar load: fF=1 -> fp32, fF=0 -> bf16
__device__ __forceinline__ float ldsel(const void* p, size_t idx, int fF){
    float r;
    if (fF) r = ((const float*)p)[idx];
    else    r = bf2f(((const unsigned short*)p)[idx]);
    return r;
}

typedef __attribute__((ext_vector_type(8))) short s8v;   // 8 bf16 (4 VGPRs)
typedef __attribute__((ext_vector_type(4))) float f4v;   // 4 fp32 accum

// ---------------------------------------------------------------------------
// k_detect: flags[0]=1 if float tensors are fp32 (else bf16);
//           flags[1]=1 if edge_index is int64 (else int32).
__global__ void k_detect(const unsigned short* __restrict__ X,
                         const int* __restrict__ ei, int* __restrict__ flags){
    __shared__ int cnt, nz;
    if (threadIdx.x == 0){ cnt = 0; nz = 0; }
    __syncthreads();
    int ok = 0;
    for (int i = threadIdx.x; i < 2048; i += 256){
        int e = (X[i] >> 7) & 0xFF;
        if (e >= 96 && e <= 160) ok++;
    }
    atomicAdd(&cnt, ok);
    int nzl = 0;
    for (int i = threadIdx.x; i < 128; i += 256)
        if (ei[2*i + 1] != 0) nzl++;
    atomicAdd(&nz, nzl);
    __syncthreads();
    if (threadIdx.x == 0){
        flags[0] = (cnt < 1843) ? 1 : 0;   // <90% plausible-bf16 => fp32
        flags[1] = (nz == 0)   ? 1 : 0;    // all odd int32 words zero => int64
    }
}

// ---------------------------------------------------------------------------
struct PackArgs {
    const void* Wx[4];
    const void* Wh[4];
    const void* bx[4];
    const void* bh[4];
};

// k_fused1 v2 (R5): re-fused preamble so the latency-bound cnt blocks overlap
// the BW-bound tobf blocks on the CUs (R4 split serialized them: +5 us).
// Block order: cnt FIRST (long pole), then tobf, then pack.
//  cnt:  off[e] = cnt[d]++ AND deg[d] += w (fire-and-forget float atomic;
//        return-less so it hides under the counter atomic's round trip).
//  tobf: XHb[node][256] bf16 = [X row | H row], 16B/lane in and out.
//  pack: W -> MFMA B lane order; bias = bx+bh.
__global__ void k_fused1(const void* __restrict__ X, const void* __restrict__ H,
                         uint4* __restrict__ XHb128,
                         const int* __restrict__ ei, const void* __restrict__ ew,
                         int* __restrict__ cnt, float* __restrict__ deg,
                         int* __restrict__ off,
                         PackArgs pa, unsigned short* __restrict__ Bp,
                         float* __restrict__ bias,
                         const int* __restrict__ flags,
                         int nbC, int nbT, int E, int N){
    int b = blockIdx.x;
    int fF = flags[0];
    if (b < nbC){
        int base = b*2048 + threadIdx.x;
        int fI = flags[1];
        int dd[8]; float wv[8];
#pragma unroll
        for (int k = 0; k < 8; k++){
            int e = base + k*256;
            dd[k] = -1; wv[k] = 0.f;
            if (e < E){
                dd[k] = fI ? ei[2*(size_t)E + 2*(size_t)e] : ei[(size_t)E + e];
                wv[k] = ldsel(ew, e, fF);
            }
        }
#pragma unroll
        for (int k = 0; k < 8; k++){
            int e = base + k*256;
            if (e < E && (unsigned)dd[k] < (unsigned)N){
                off[e] = atomicAdd(&cnt[dd[k]], 1);
                atomicAdd(&deg[dd[k]], wv[k]);
            }
        }
    } else if (b < nbC + nbT){
        int t = (b - nbC)*256 + threadIdx.x;
        if (t >= N*32) return;
        int n = t >> 5, i = t & 31;
        int q = (i < 16) ? i : i - 16;
        uint4 o;
        if (fF){
            const float4* src = (const float4*)((i < 16) ? X : H);
            float4 a = src[(size_t)n*32 + q*2];
            float4 bb = src[(size_t)n*32 + q*2 + 1];
            o.x = ((unsigned int)f2bf(a.y) << 16) | f2bf(a.x);
            o.y = ((unsigned int)f2bf(a.w) << 16) | f2bf(a.z);
            o.z = ((unsigned int)f2bf(bb.y) << 16) | f2bf(bb.x);
            o.w = ((unsigned int)f2bf(bb.w) << 16) | f2bf(bb.z);
        } else {
            const uint4* src = (const uint4*)((i < 16) ? X : H);
            o = src[(size_t)n*16 + q];
        }
        XHb128[(size_t)n*32 + i] = o;
    } else {
        int t = (b - nbC - nbT)*256 + threadIdx.x;
        if (t < 4*8*8*64*8){
            int j    =  t        & 7;
            int lane = (t >> 3)  & 63;
            int kb   = (t >> 9)  & 7;
            int ct   = (t >> 12) & 7;
            int g    = (t >> 15) & 3;
            int k   = kb*32 + (lane >> 4)*8 + j;
            int col = ct*16 + (lane & 15);
            const void* p; size_t idx;
            if (k < 128){ p = pa.Wx[g]; idx = (size_t)k*128 + col; }
            else        { p = pa.Wh[g]; idx = (size_t)(k-128)*128 + col; }
            unsigned short v;
            if (fF) v = f2bf(((const float*)p)[idx]);
            else    v = ((const unsigned short*)p)[idx];
            Bp[t] = v;
        }
        if (t < 512){
            int g = t >> 7, c = t & 127;
            bias[t] = ldsel(pa.bx[g], c, fF) + ldsel(pa.bh[g], c, fF);
        }
    }
}

// ---------------------------------------------------------------------------
// parallel scan trio: rowstart = exclusive_scan(cnt), rowstart[n] = total
__global__ void k_scanA(const int* __restrict__ cnt, int* __restrict__ bsum, int n){
    __shared__ int sh[256];
    int t = threadIdx.x, i = blockIdx.x * 256 + t;
    sh[t] = (i < n) ? cnt[i] : 0;
    __syncthreads();
    for (int o = 128; o > 0; o >>= 1){
        if (t < o) sh[t] += sh[t + o];
        __syncthreads();
    }
    if (t == 0) bsum[blockIdx.x] = sh[0];
}
__global__ void k_scanB(const int* __restrict__ bsum, int* __restrict__ bsumoff, int nb){
    __shared__ int sh[256];
    int t = threadIdx.x;
    int v = (t < nb) ? bsum[t] : 0;
    sh[t] = v;
    __syncthreads();
    for (int o = 1; o < 256; o <<= 1){
        int u = (t >= o) ? sh[t - o] : 0;
        __syncthreads();
        sh[t] += u;
        __syncthreads();
    }
    bsumoff[t] = sh[t] - v;
}
// scanC also materializes dis = rsqrt(deg) (R5: k_degdis deleted; deg is
// accumulated by k_fused1's cnt segment).
__global__ void k_scanC(const int* __restrict__ cnt, const int* __restrict__ bsumoff,
                        const float* __restrict__ deg,
                        int* __restrict__ rowstart, float* __restrict__ dis, int n){
    __shared__ int sh[256];
    int t = threadIdx.x, i = blockIdx.x * 256 + t;
    int v = (i < n) ? cnt[i] : 0;
    sh[t] = v;
    __syncthreads();
    for (int o = 1; o < 256; o <<= 1){
        int u = (t >= o) ? sh[t - o] : 0;
        __syncthreads();
        sh[t] += u;
        __syncthreads();
    }
    int incl = sh[t];
    if (i < n){
        rowstart[i] = bsumoff[blockIdx.x] + incl - v;
        float dg = deg[i];
        dis[i] = (dg > 0.f) ? rsqrtf(dg) : 0.f;
    }
    if (i == n-1)  rowstart[n] = bsumoff[blockIdx.x] + incl;
}

// ---------------------------------------------------------------------------
// k_scatter: recs[rowstart[d]+off[e]] = {src, w}; 4-edge batched ILP (R5).
__global__ void k_scatter(const int* __restrict__ ei, const void* __restrict__ ew,
                          const int* __restrict__ rowstart, const int* __restrict__ off,
                          int2* __restrict__ recs, const int* __restrict__ flags,
                          int E, int N){
    int base = blockIdx.x*1024 + threadIdx.x;
    int fF = flags[0], fI = flags[1];
    int ss[4], dd[4], oo[4]; float wv[4];
#pragma unroll
    for (int k = 0; k < 4; k++){
        int e = base + k*256;
        dd[k] = -1; ss[k] = 0; wv[k] = 0.f; oo[k] = 0;
        if (e < E){
            if (fI){ ss[k] = ei[2*(size_t)e]; dd[k] = ei[2*(size_t)E + 2*(size_t)e]; }
            else   { ss[k] = ei[e];           dd[k] = ei[(size_t)E + e]; }
            oo[k] = off[e];
            if ((unsigned)ss[k] < (unsigned)N) wv[k] = ldsel(ew, e, fF);
            else ss[k] = 0;
        }
    }
#pragma unroll
    for (int k = 0; k < 4; k++){
        if ((unsigned)dd[k] < (unsigned)N){
            int2 r; r.x = ss[k]; r.y = __float_as_int(wv[k]);
            recs[rowstart[dd[k]] + oo[k]] = r;
        }
    }
}

// ---------------------------------------------------------------------------
// k_gather v4 (R5): ONE wave per node; lane-pair edges (lanes 0-31 edge i,
// lanes 32-63 edge i+1), uint4 (16B) per lane. 8-edge unroll = 4 uint4 row
// loads in flight per half-wave (R3 x2-unroll under-delivered at VGPR=24;
// push MLP further). Cross-half merge: 8 shfl_xor(32) once per node.
__global__ __launch_bounds__(256)
void k_gather(const int2* __restrict__ recs, const int* __restrict__ rowstart,
              const float* __restrict__ dis, const uint4* __restrict__ XHb128,
              uint4* __restrict__ AXH128, int N){
    int node = (blockIdx.x * 256 + threadIdx.x) >> 6;
    int lane = threadIdx.x & 63;
    if (node >= N) return;
    int half = lane >> 5;      // edge of the pair
    int sub  = lane & 31;      // 16B chunk within row
    int beg = rowstart[node], end = rowstart[node + 1];
    float disd = dis[node];
    float a0=0.f,a1=0.f,a2=0.f,a3=0.f,a4=0.f,a5=0.f,a6=0.f,a7=0.f;

#define ACC8(v, n)                                              \
    a0 += (n) * bf2f((unsigned short)((v).x & 0xffff));         \
    a1 += (n) * bf2f((unsigned short)((v).x >> 16));            \
    a2 += (n) * bf2f((unsigned short)((v).y & 0xffff));         \
    a3 += (n) * bf2f((unsigned short)((v).y >> 16));            \
    a4 += (n) * bf2f((unsigned short)((v).z & 0xffff));         \
    a5 += (n) * bf2f((unsigned short)((v).z >> 16));            \
    a6 += (n) * bf2f((unsigned short)((v).w & 0xffff));         \
    a7 += (n) * bf2f((unsigned short)((v).w >> 16));

    int i = beg;
    for (; i + 7 < end; i += 8){
        int2 rA = recs[i     + half];
        int2 rB = recs[i + 2 + half];
        int2 rC = recs[i + 4 + half];
        int2 rD = recs[i + 6 + half];
        uint4 vA = XHb128[(size_t)rA.x*32 + sub];
        uint4 vB = XHb128[(size_t)rB.x*32 + sub];
        uint4 vC = XHb128[(size_t)rC.x*32 + sub];
        uint4 vD = XHb128[(size_t)rD.x*32 + sub];
        float nA = dis[rA.x] * __int_as_float(rA.y) * disd;
        float nB = dis[rB.x] * __int_as_float(rB.y) * disd;
        float nC = dis[rC.x] * __int_as_float(rC.y) * disd;
        float nD = dis[rD.x] * __int_as_float(rD.y) * disd;
        ACC8(vA, nA);
        ACC8(vB, nB);
        ACC8(vC, nC);
        ACC8(vD, nD);
    }
    for (; i + 1 < end; i += 2){
        int2 rA = recs[i + half];
        uint4 vA = XHb128[(size_t)rA.x*32 + sub];
        float nA = dis[rA.x] * __int_as_float(rA.y) * disd;
        ACC8(vA, nA);
    }
    if (i < end){   // one edge left: both halves read it, half 1 contributes 0
        int2 rA = recs[i];
        uint4 vA = XHb128[(size_t)rA.x*32 + sub];
        float nA = (half == 0) ? dis[rA.x] * __int_as_float(rA.y) * disd : 0.f;
        ACC8(vA, nA);
    }
#undef ACC8

    a0 += __shfl_xor(a0, 32, 64);
    a1 += __shfl_xor(a1, 32, 64);
    a2 += __shfl_xor(a2, 32, 64);
    a3 += __shfl_xor(a3, 32, 64);
    a4 += __shfl_xor(a4, 32, 64);
    a5 += __shfl_xor(a5, 32, 64);
    a6 += __shfl_xor(a6, 32, 64);
    a7 += __shfl_xor(a7, 32, 64);

    if (half == 0){
        uint4 o;
        o.x = ((unsigned int)f2bf(a1) << 16) | f2bf(a0);
        o.y = ((unsigned int)f2bf(a3) << 16) | f2bf(a2);
        o.z = ((unsigned int)f2bf(a5) << 16) | f2bf(a4);
        o.w = ((unsigned int)f2bf(a7) << 16) | f2bf(a6);
        AXH128[(size_t)node*32 + sub] = o;
    }
}

// ---------------------------------------------------------------------------
struct EpiArgs {
    const void *C, *wci, *wcf, *wco, *bi, *bff, *bc, *bo;
};

// k_gemm v2: 32 nodes/block (2 M-tiles), 4 waves; wave w owns channel slice
// [w*32, w*32+32) of ALL FOUR gates -> LSTM epilogue fully in-register
// (no LDS, no syncthreads).
__global__ __launch_bounds__(256)
void k_gemm(const unsigned short* __restrict__ AXH,
            const unsigned short* __restrict__ Bp, const float* __restrict__ bias,
            EpiArgs ea, void* __restrict__ outp, const int* __restrict__ flags, int N){
    int tid  = threadIdx.x;
    int w    = tid >> 6, lane = tid & 63;
    int node0 = blockIdx.x * 32;
    int fF = flags[0];

    // acc[m][ct8]: m = M-tile (16 nodes), ct8 = g*2+sub (gate g, 16-col half sub)
    f4v acc[2][8];
#pragma unroll
    for (int m = 0; m < 2; m++)
#pragma unroll
        for (int c = 0; c < 8; c++) acc[m][c] = (f4v){0.f,0.f,0.f,0.f};

    const unsigned short* a0base = AXH + (size_t)(node0 + (lane & 15))*256 + (lane >> 4)*8;
    const unsigned short* a1base = a0base + 16*256;
#pragma unroll
    for (int kb = 0; kb < 8; kb++){
        s8v af0 = *(const s8v*)(a0base + kb*32);
        s8v af1 = *(const s8v*)(a1base + kb*32);
#pragma unroll
        for (int ct8 = 0; ct8 < 8; ct8++){
            int g = ct8 >> 1, sub = ct8 & 1;
            const s8v bfrag = *(const s8v*)(Bp + g*32768 + (size_t)(w*2 + sub)*4096
                                            + kb*512 + lane*8);
            acc[0][ct8] = __builtin_amdgcn_mfma_f32_16x16x32_bf16(af0, bfrag, acc[0][ct8], 0, 0, 0);
            acc[1][ct8] = __builtin_amdgcn_mfma_f32_16x16x32_bf16(af1, bfrag, acc[1][ct8], 0, 0, 0);
        }
    }

    // D layout: col = lane&15 (within 16-col tile), row = (lane>>4)*4 + r
    int q = lane >> 4, cl = lane & 15;
#pragma unroll
    for (int sub = 0; sub < 2; sub++){
        int c = w*32 + sub*16 + cl;            // channel in [0,128)
        float bvi = bias[0*128 + c], bvf = bias[1*128 + c];
        float bvc = bias[2*128 + c], bvo = bias[3*128 + c];
        float wci = ldsel(ea.wci, c, fF), wcf = ldsel(ea.wcf, c, fF), wco = ldsel(ea.wco, c, fF);
        float bi  = ldsel(ea.bi, c, fF),  bff = ldsel(ea.bff, c, fF);
        float bc  = ldsel(ea.bc, c, fF),  bo  = ldsel(ea.bo, c, fF);
#pragma unroll
        for (int m = 0; m < 2; m++){
#pragma unroll
            for (int r = 0; r < 4; r++){
                int node = node0 + m*16 + q*4 + r;
                if (node >= N) continue;
                size_t gidx = (size_t)node*128 + c;
                float Cv = ldsel(ea.C, gidx, fF);
                float pi  = acc[m][0+sub][r] + bvi;
                float pf  = acc[m][2+sub][r] + bvf;
                float pcv = acc[m][4+sub][r] + bvc;
                float po  = acc[m][6+sub][r] + bvo;
                float Iv = sigm(pi + wci*Cv + bi);
                float Fv = sigm(pf + wcf*Cv + bff);
                float Tv = tanhf(pcv + bc);
                float Cn = Fv*Cv + Iv*Tv;
                float Ov = sigm(po + wco*Cn + bo);
                float Hn = Ov * tanhf(Cn);
                if (fF){
                    ((float*)outp)[gidx] = Hn;
                    ((float*)outp)[(size_t)N*128 + gidx] = Cn;
                } else {
                    ((unsigned short*)outp)[gidx] = f2bf(Hn);
                    ((unsigned short*)outp)[(size_t)N*128 + gidx] = f2bf(Cn);
                }
            }
        }
    }
}

// ---------------------------------------------------------------------------
extern "C" void kernel_launch(void* const* d_in, const int* in_sizes, int n_in,
                              void* d_out, int out_size, void* d_ws, size_t ws_size,
                              hipStream_t stream){
    const void* X  = d_in[0];
    const int*  ei = (const int*)d_in[1];
    const void* ew = d_in[2];
    const void* H  = d_in[3];
    const void* C  = d_in[4];
    const int N = in_sizes[0] / 128;
    const int E = in_sizes[2];

    // workspace layout (bytes), peak ~66.6 MB:
    // [0,256K) cnt | [256K,512K) deg  (zeroed together, one 512K memset)
    // [512K,768K) rowstart | [768K] bsum(1K) | [772K] bsumoff(1K) | [776K] flags(8B)
    // [780K,980K) dis
    // [1M,1.25M) Bp | [1.25M] bias(2K)
    // [2M,8.4M) off (dead after k_scatter)
    // [2M,27.6M) AXH (aliases off; written by k_gather after scatter)
    // [28M,40.8M) recs | [41M,66.6M) XHb
    char* ws = (char*)d_ws;
    int*   cnt          = (int*)  (ws);
    float* deg          = (float*)(ws + ((size_t)256 << 10));
    int*   rowstart     = (int*)  (ws + ((size_t)512 << 10));
    int*   bsum         = (int*)  (ws + ((size_t)768 << 10));
    int*   bsumoff      = (int*)  (ws + ((size_t)772 << 10));
    int*   flags        = (int*)  (ws + ((size_t)776 << 10));
    float* dis          = (float*)(ws + ((size_t)780 << 10));
    unsigned short* Bp  = (unsigned short*)(ws + ((size_t)1 << 20));
    float* bias         = (float*)(ws + ((size_t)1 << 20) + ((size_t)256 << 10));
    int*   off          = (int*)  (ws + ((size_t)2 << 20));
    unsigned int* AXH32 = (unsigned int*)(ws + ((size_t)2 << 20));
    int2*  recs         = (int2*) (ws + ((size_t)28 << 20));
    unsigned int* XHb32 = (unsigned int*)(ws + ((size_t)41 << 20));

    hipMemsetAsync(cnt, 0, (size_t)512 << 10, stream);   // cnt + deg
    k_detect<<<1, 256, 0, stream>>>((const unsigned short*)X, ei, flags);

    PackArgs pa;
    pa.Wx[0]=d_in[5];  pa.bx[0]=d_in[6];  pa.Wh[0]=d_in[7];  pa.bh[0]=d_in[8];
    pa.Wx[1]=d_in[9];  pa.bx[1]=d_in[10]; pa.Wh[1]=d_in[11]; pa.bh[1]=d_in[12];
    pa.Wx[2]=d_in[13]; pa.bx[2]=d_in[14]; pa.Wh[2]=d_in[15]; pa.bh[2]=d_in[16];
    pa.Wx[3]=d_in[17]; pa.bx[3]=d_in[18]; pa.Wh[3]=d_in[19]; pa.bh[3]=d_in[20];

    int nbC = (E + 2047)/2048;        // cnt blocks (8 edges/thread)
    int nbT = (N*32 + 255)/256;       // tobf blocks (16B/lane)
    k_fused1<<<nbC + nbT + 512, 256, 0, stream>>>(X, H, (uint4*)XHb32, ei, ew,
                                                  cnt, deg, off, pa, Bp, bias,
                                                  flags, nbC, nbT, E, N);

    int nbA = (N + 255)/256;
    k_scanA<<<nbA, 256, 0, stream>>>(cnt, bsum, N);
    k_scanB<<<1, 256, 0, stream>>>(bsum, bsumoff, nbA);
    k_scanC<<<nbA, 256, 0, stream>>>(cnt, bsumoff, deg, rowstart, dis, N);

    k_scatter<<<(E + 1023)/1024, 256, 0, stream>>>(ei, ew, rowstart, off, recs, flags, E, N);
    k_gather<<<(N*64 + 255)/256, 256, 0, stream>>>(recs, rowstart, dis,
                                                   (const uint4*)XHb32,
                                                   (uint4*)AXH32, N);

    EpiArgs ea;
    ea.C   = C;
    ea.wci = d_in[21];
    ea.wcf = d_in[22];
    ea.wco = d_in[23];
    ea.bi  = d_in[24];
    ea.bff = d_in[25];
    ea.bc  = d_in[26];
    ea.bo  = d_in[27];
    k_gemm<<<(N + 31)/32, 256, 0, stream>>>((const unsigned short*)AXH32, Bp, bias,
                                            ea, d_out, flags, N);
}

// Round 7
// 474.866 us; speedup vs baseline: 1.1598x; 1.1598x over previous
//
#include <hip/hip_runtime.h>

// ---------- bf16 helpers ----------
__device__ __forceinline__ float bf2f(unsigned short u){
    union { unsigned int i; float f; } v; v.i = ((unsigned int)u) << 16; return v.f;
}
__device__ __forceinline__ unsigned short f2bf(float f){
    union { unsigned int i; float f; } v; v.f = f;
    unsigned int i = v.i;
    unsigned int r = i + 0x7FFFu + ((i >> 16) & 1u);   // round-nearest-even
    return (unsigned short)(r >> 16);
}
__device__ __forceinline__ float sigm(float x){ return 1.0f / (1.0f + __expf(-x)); }

// flag-dispatched scalar load: fF=1 -> fp32, fF=0 -> bf16
__device__ __forceinline__ float ldsel(const void* p, size_t idx, int fF){
    float r;
    if (fF) r = ((const float*)p)[idx];
    else    r = bf2f(((const unsigned short*)p)[idx]);
    return r;
}

typedef __attribute__((ext_vector_type(8))) short s8v;   // 8 bf16 (4 VGPRs)
typedef __attribute__((ext_vector_type(4))) float f4v;   // 4 fp32 accum

// ---------------------------------------------------------------------------
// k_detect: flags[0]=1 if float tensors are fp32 (else bf16);
//           flags[1]=1 if edge_index is int64 (else int32).
__global__ void k_detect(const unsigned short* __restrict__ X,
                         const int* __restrict__ ei, int* __restrict__ flags){
    __shared__ int cnt, nz;
    if (threadIdx.x == 0){ cnt = 0; nz = 0; }
    __syncthreads();
    int ok = 0;
    for (int i = threadIdx.x; i < 2048; i += 256){
        int e = (X[i] >> 7) & 0xFF;
        if (e >= 96 && e <= 160) ok++;
    }
    atomicAdd(&cnt, ok);
    int nzl = 0;
    for (int i = threadIdx.x; i < 128; i += 256)
        if (ei[2*i + 1] != 0) nzl++;
    atomicAdd(&nz, nzl);
    __syncthreads();
    if (threadIdx.x == 0){
        flags[0] = (cnt < 1843) ? 1 : 0;   // <90% plausible-bf16 => fp32
        flags[1] = (nz == 0)   ? 1 : 0;    // all odd int32 words zero => int64
    }
}

// ---------------------------------------------------------------------------
struct PackArgs {
    const void* Wx[4];
    const void* Wh[4];
    const void* bx[4];
    const void* bh[4];
};

// k_fused1 v3 (R7): fused preamble; cnt segment uses ONE 64-bit packed atomic
// per edge: high32 = count (+1<<32), low32 = w in 24-bit fixed point.
// R6 proved the pass is atomic-THROUGHPUT-bound (2 atomics/edge = x1.7 time),
// so deg must ride the SAME atomic, not a second one. off[e] = return>>32.
//  tobf: XHb[node][256] bf16 = [X row | H row], 16B/lane in and out.
//  pack: W -> MFMA B lane order; bias = bx+bh.
__global__ void k_fused1(const void* __restrict__ X, const void* __restrict__ H,
                         uint4* __restrict__ XHb128,
                         const int* __restrict__ ei, const void* __restrict__ ew,
                         unsigned long long* __restrict__ pk,
                         int* __restrict__ off,
                         PackArgs pa, unsigned short* __restrict__ Bp,
                         float* __restrict__ bias,
                         const int* __restrict__ flags,
                         int nbC, int nbT, int E, int N){
    int b = blockIdx.x;
    int fF = flags[0];
    if (b < nbC){
        int base = b*2048 + threadIdx.x;
        int fI = flags[1];
        int dd[8]; unsigned long long pv[8];
#pragma unroll
        for (int k = 0; k < 8; k++){
            int e = base + k*256;
            dd[k] = -1; pv[k] = 0;
            if (e < E){
                dd[k] = fI ? ei[2*(size_t)E + 2*(size_t)e] : ei[(size_t)E + e];
                float w = ldsel(ew, e, fF);
                unsigned int wfix = (unsigned int)(w * 16777216.0f + 0.5f);
                pv[k] = (1ULL << 32) | (unsigned long long)wfix;
            }
        }
#pragma unroll
        for (int k = 0; k < 8; k++){
            int e = base + k*256;
            if (e < E && (unsigned)dd[k] < (unsigned)N){
                unsigned long long old = atomicAdd(&pk[dd[k]], pv[k]);
                off[e] = (int)(old >> 32);
            }
        }
    } else if (b < nbC + nbT){
        int t = (b - nbC)*256 + threadIdx.x;
        if (t >= N*32) return;
        int n = t >> 5, i = t & 31;
        int q = (i < 16) ? i : i - 16;
        uint4 o;
        if (fF){
            const float4* src = (const float4*)((i < 16) ? X : H);
            float4 a = src[(size_t)n*32 + q*2];
            float4 bb = src[(size_t)n*32 + q*2 + 1];
            o.x = ((unsigned int)f2bf(a.y) << 16) | f2bf(a.x);
            o.y = ((unsigned int)f2bf(a.w) << 16) | f2bf(a.z);
            o.z = ((unsigned int)f2bf(bb.y) << 16) | f2bf(bb.x);
            o.w = ((unsigned int)f2bf(bb.w) << 16) | f2bf(bb.z);
        } else {
            const uint4* src = (const uint4*)((i < 16) ? X : H);
            o = src[(size_t)n*16 + q];
        }
        XHb128[(size_t)n*32 + i] = o;
    } else {
        int t = (b - nbC - nbT)*256 + threadIdx.x;
        if (t < 4*8*8*64*8){
            int j    =  t        & 7;
            int lane = (t >> 3)  & 63;
            int kb   = (t >> 9)  & 7;
            int ct   = (t >> 12) & 7;
            int g    = (t >> 15) & 3;
            int k   = kb*32 + (lane >> 4)*8 + j;
            int col = ct*16 + (lane & 15);
            const void* p; size_t idx;
            if (k < 128){ p = pa.Wx[g]; idx = (size_t)k*128 + col; }
            else        { p = pa.Wh[g]; idx = (size_t)(k-128)*128 + col; }
            unsigned short v;
            if (fF) v = f2bf(((const float*)p)[idx]);
            else    v = ((const unsigned short*)p)[idx];
            Bp[t] = v;
        }
        if (t < 512){
            int g = t >> 7, c = t & 127;
            bias[t] = ldsel(pa.bx[g], c, fF) + ldsel(pa.bh[g], c, fF);
        }
    }
}

// ---------------------------------------------------------------------------
// parallel scan trio over packed counters: rowstart = exclusive_scan(hi32),
// rowstart[n] = total; scanC also materializes dis = rsqrt(lo32 * 2^-24).
__global__ void k_scanA(const unsigned long long* __restrict__ pk,
                        int* __restrict__ bsum, int n){
    __shared__ int sh[256];
    int t = threadIdx.x, i = blockIdx.x * 256 + t;
    sh[t] = (i < n) ? (int)(pk[i] >> 32) : 0;
    __syncthreads();
    for (int o = 128; o > 0; o >>= 1){
        if (t < o) sh[t] += sh[t + o];
        __syncthreads();
    }
    if (t == 0) bsum[blockIdx.x] = sh[0];
}
__global__ void k_scanB(const int* __restrict__ bsum, int* __restrict__ bsumoff, int nb){
    __shared__ int sh[256];
    int t = threadIdx.x;
    int v = (t < nb) ? bsum[t] : 0;
    sh[t] = v;
    __syncthreads();
    for (int o = 1; o < 256; o <<= 1){
        int u = (t >= o) ? sh[t - o] : 0;
        __syncthreads();
        sh[t] += u;
        __syncthreads();
    }
    bsumoff[t] = sh[t] - v;
}
__global__ void k_scanC(const unsigned long long* __restrict__ pk,
                        const int* __restrict__ bsumoff,
                        int* __restrict__ rowstart, float* __restrict__ dis, int n){
    __shared__ int sh[256];
    int t = threadIdx.x, i = blockIdx.x * 256 + t;
    unsigned long long pv = (i < n) ? pk[i] : 0ULL;
    int v = (int)(pv >> 32);
    sh[t] = v;
    __syncthreads();
    for (int o = 1; o < 256; o <<= 1){
        int u = (t >= o) ? sh[t - o] : 0;
        __syncthreads();
        sh[t] += u;
        __syncthreads();
    }
    int incl = sh[t];
    if (i < n){
        rowstart[i] = bsumoff[blockIdx.x] + incl - v;
        float dg = (float)(unsigned int)pv * (1.0f/16777216.0f);
        dis[i] = (dg > 0.f) ? rsqrtf(dg) : 0.f;
    }
    if (i == n-1)  rowstart[n] = bsumoff[blockIdx.x] + incl;
}

// ---------------------------------------------------------------------------
// k_scatter: recs[rowstart[d]+off[e]] = {src, w}; 4-edge batched ILP (R5).
__global__ void k_scatter(const int* __restrict__ ei, const void* __restrict__ ew,
                          const int* __restrict__ rowstart, const int* __restrict__ off,
                          int2* __restrict__ recs, const int* __restrict__ flags,
                          int E, int N){
    int base = blockIdx.x*1024 + threadIdx.x;
    int fF = flags[0], fI = flags[1];
    int ss[4], dd[4], oo[4]; float wv[4];
#pragma unroll
    for (int k = 0; k < 4; k++){
        int e = base + k*256;
        dd[k] = -1; ss[k] = 0; wv[k] = 0.f; oo[k] = 0;
        if (e < E){
            if (fI){ ss[k] = ei[2*(size_t)e]; dd[k] = ei[2*(size_t)E + 2*(size_t)e]; }
            else   { ss[k] = ei[e];           dd[k] = ei[(size_t)E + e]; }
            oo[k] = off[e];
            if ((unsigned)ss[k] < (unsigned)N) wv[k] = ldsel(ew, e, fF);
            else ss[k] = 0;
        }
    }
#pragma unroll
    for (int k = 0; k < 4; k++){
        if ((unsigned)dd[k] < (unsigned)N){
            int2 r; r.x = ss[k]; r.y = __float_as_int(wv[k]);
            recs[rowstart[dd[k]] + oo[k]] = r;
        }
    }
}

// ---------------------------------------------------------------------------
// k_gather v4 (R5): ONE wave per node; lane-pair edges (lanes 0-31 edge i,
// lanes 32-63 edge i+1), uint4 (16B) per lane. 8-edge unroll = 4 uint4 row
// loads in flight per half-wave. Cross-half merge: 8 shfl_xor(32) per node.
__global__ __launch_bounds__(256)
void k_gather(const int2* __restrict__ recs, const int* __restrict__ rowstart,
              const float* __restrict__ dis, const uint4* __restrict__ XHb128,
              uint4* __restrict__ AXH128, int N){
    int node = (blockIdx.x * 256 + threadIdx.x) >> 6;
    int lane = threadIdx.x & 63;
    if (node >= N) return;
    int half = lane >> 5;      // edge of the pair
    int sub  = lane & 31;      // 16B chunk within row
    int beg = rowstart[node], end = rowstart[node + 1];
    float disd = dis[node];
    float a0=0.f,a1=0.f,a2=0.f,a3=0.f,a4=0.f,a5=0.f,a6=0.f,a7=0.f;

#define ACC8(v, n)                                              \
    a0 += (n) * bf2f((unsigned short)((v).x & 0xffff));         \
    a1 += (n) * bf2f((unsigned short)((v).x >> 16));            \
    a2 += (n) * bf2f((unsigned short)((v).y & 0xffff));         \
    a3 += (n) * bf2f((unsigned short)((v).y >> 16));            \
    a4 += (n) * bf2f((unsigned short)((v).z & 0xffff));         \
    a5 += (n) * bf2f((unsigned short)((v).z >> 16));            \
    a6 += (n) * bf2f((unsigned short)((v).w & 0xffff));         \
    a7 += (n) * bf2f((unsigned short)((v).w >> 16));

    int i = beg;
    for (; i + 7 < end; i += 8){
        int2 rA = recs[i     + half];
        int2 rB = recs[i + 2 + half];
        int2 rC = recs[i + 4 + half];
        int2 rD = recs[i + 6 + half];
        uint4 vA = XHb128[(size_t)rA.x*32 + sub];
        uint4 vB = XHb128[(size_t)rB.x*32 + sub];
        uint4 vC = XHb128[(size_t)rC.x*32 + sub];
        uint4 vD = XHb128[(size_t)rD.x*32 + sub];
        float nA = dis[rA.x] * __int_as_float(rA.y) * disd;
        float nB = dis[rB.x] * __int_as_float(rB.y) * disd;
        float nC = dis[rC.x] * __int_as_float(rC.y) * disd;
        float nD = dis[rD.x] * __int_as_float(rD.y) * disd;
        ACC8(vA, nA);
        ACC8(vB, nB);
        ACC8(vC, nC);
        ACC8(vD, nD);
    }
    for (; i + 1 < end; i += 2){
        int2 rA = recs[i + half];
        uint4 vA = XHb128[(size_t)rA.x*32 + sub];
        float nA = dis[rA.x] * __int_as_float(rA.y) * disd;
        ACC8(vA, nA);
    }
    if (i < end){   // one edge left: both halves read it, half 1 contributes 0
        int2 rA = recs[i];
        uint4 vA = XHb128[(size_t)rA.x*32 + sub];
        float nA = (half == 0) ? dis[rA.x] * __int_as_float(rA.y) * disd : 0.f;
        ACC8(vA, nA);
    }
#undef ACC8

    a0 += __shfl_xor(a0, 32, 64);
    a1 += __shfl_xor(a1, 32, 64);
    a2 += __shfl_xor(a2, 32, 64);
    a3 += __shfl_xor(a3, 32, 64);
    a4 += __shfl_xor(a4, 32, 64);
    a5 += __shfl_xor(a5, 32, 64);
    a6 += __shfl_xor(a6, 32, 64);
    a7 += __shfl_xor(a7, 32, 64);

    if (half == 0){
        uint4 o;
        o.x = ((unsigned int)f2bf(a1) << 16) | f2bf(a0);
        o.y = ((unsigned int)f2bf(a3) << 16) | f2bf(a2);
        o.z = ((unsigned int)f2bf(a5) << 16) | f2bf(a4);
        o.w = ((unsigned int)f2bf(a7) << 16) | f2bf(a6);
        AXH128[(size_t)node*32 + sub] = o;
    }
}

// ---------------------------------------------------------------------------
struct EpiArgs {
    const void *C, *wci, *wcf, *wco, *bi, *bff, *bc, *bo;
};

// k_gemm v2: 32 nodes/block (2 M-tiles), 4 waves; wave w owns channel slice
// [w*32, w*32+32) of ALL FOUR gates -> LSTM epilogue fully in-register
// (no LDS, no syncthreads).
__global__ __launch_bounds__(256)
void k_gemm(const unsigned short* __restrict__ AXH,
            const unsigned short* __restrict__ Bp, const float* __restrict__ bias,
            EpiArgs ea, void* __restrict__ outp, const int* __restrict__ flags, int N){
    int tid  = threadIdx.x;
    int w    = tid >> 6, lane = tid & 63;
    int node0 = blockIdx.x * 32;
    int fF = flags[0];

    // acc[m][ct8]: m = M-tile (16 nodes), ct8 = g*2+sub (gate g, 16-col half sub)
    f4v acc[2][8];
#pragma unroll
    for (int m = 0; m < 2; m++)
#pragma unroll
        for (int c = 0; c < 8; c++) acc[m][c] = (f4v){0.f,0.f,0.f,0.f};

    const unsigned short* a0base = AXH + (size_t)(node0 + (lane & 15))*256 + (lane >> 4)*8;
    const unsigned short* a1base = a0base + 16*256;
#pragma unroll
    for (int kb = 0; kb < 8; kb++){
        s8v af0 = *(const s8v*)(a0base + kb*32);
        s8v af1 = *(const s8v*)(a1base + kb*32);
#pragma unroll
        for (int ct8 = 0; ct8 < 8; ct8++){
            int g = ct8 >> 1, sub = ct8 & 1;
            const s8v bfrag = *(const s8v*)(Bp + g*32768 + (size_t)(w*2 + sub)*4096
                                            + kb*512 + lane*8);
            acc[0][ct8] = __builtin_amdgcn_mfma_f32_16x16x32_bf16(af0, bfrag, acc[0][ct8], 0, 0, 0);
            acc[1][ct8] = __builtin_amdgcn_mfma_f32_16x16x32_bf16(af1, bfrag, acc[1][ct8], 0, 0, 0);
        }
    }

    // D layout: col = lane&15 (within 16-col tile), row = (lane>>4)*4 + r
    int q = lane >> 4, cl = lane & 15;
#pragma unroll
    for (int sub = 0; sub < 2; sub++){
        int c = w*32 + sub*16 + cl;            // channel in [0,128)
        float bvi = bias[0*128 + c], bvf = bias[1*128 + c];
        float bvc = bias[2*128 + c], bvo = bias[3*128 + c];
        float wci = ldsel(ea.wci, c, fF), wcf = ldsel(ea.wcf, c, fF), wco = ldsel(ea.wco, c, fF);
        float bi  = ldsel(ea.bi, c, fF),  bff = ldsel(ea.bff, c, fF);
        float bc  = ldsel(ea.bc, c, fF),  bo  = ldsel(ea.bo, c, fF);
#pragma unroll
        for (int m = 0; m < 2; m++){
#pragma unroll
            for (int r = 0; r < 4; r++){
                int node = node0 + m*16 + q*4 + r;
                if (node >= N) continue;
                size_t gidx = (size_t)node*128 + c;
                float Cv = ldsel(ea.C, gidx, fF);
                float pi  = acc[m][0+sub][r] + bvi;
                float pf  = acc[m][2+sub][r] + bvf;
                float pcv = acc[m][4+sub][r] + bvc;
                float po  = acc[m][6+sub][r] + bvo;
                float Iv = sigm(pi + wci*Cv + bi);
                float Fv = sigm(pf + wcf*Cv + bff);
                float Tv = tanhf(pcv + bc);
                float Cn = Fv*Cv + Iv*Tv;
                float Ov = sigm(po + wco*Cn + bo);
                float Hn = Ov * tanhf(Cn);
                if (fF){
                    ((float*)outp)[gidx] = Hn;
                    ((float*)outp)[(size_t)N*128 + gidx] = Cn;
                } else {
                    ((unsigned short*)outp)[gidx] = f2bf(Hn);
                    ((unsigned short*)outp)[(size_t)N*128 + gidx] = f2bf(Cn);
                }
            }
        }
    }
}

// ---------------------------------------------------------------------------
extern "C" void kernel_launch(void* const* d_in, const int* in_sizes, int n_in,
                              void* d_out, int out_size, void* d_ws, size_t ws_size,
                              hipStream_t stream){
    const void* X  = d_in[0];
    const int*  ei = (const int*)d_in[1];
    const void* ew = d_in[2];
    const void* H  = d_in[3];
    const void* C  = d_in[4];
    const int N = in_sizes[0] / 128;
    const int E = in_sizes[2];

    // workspace layout (bytes), peak ~66.6 MB:
    // [0,512K) pk (u64 packed count|deg, 400KB used; zeroed in one memset)
    // [512K,768K) rowstart | [768K] bsum(1K) | [772K] bsumoff(1K) | [776K] flags(8B)
    // [780K,980K) dis
    // [1M,1.25M) Bp | [1.25M] bias(2K)
    // [2M,8.4M) off (dead after k_scatter)
    // [2M,27.6M) AXH (aliases off; written by k_gather after scatter)
    // [28M,40.8M) recs | [41M,66.6M) XHb
    char* ws = (char*)d_ws;
    unsigned long long* pk = (unsigned long long*)(ws);
    int*   rowstart     = (int*)  (ws + ((size_t)512 << 10));
    int*   bsum         = (int*)  (ws + ((size_t)768 << 10));
    int*   bsumoff      = (int*)  (ws + ((size_t)772 << 10));
    int*   flags        = (int*)  (ws + ((size_t)776 << 10));
    float* dis          = (float*)(ws + ((size_t)780 << 10));
    unsigned short* Bp  = (unsigned short*)(ws + ((size_t)1 << 20));
    float* bias         = (float*)(ws + ((size_t)1 << 20) + ((size_t)256 << 10));
    int*   off          = (int*)  (ws + ((size_t)2 << 20));
    unsigned int* AXH32 = (unsigned int*)(ws + ((size_t)2 << 20));
    int2*  recs         = (int2*) (ws + ((size_t)28 << 20));
    unsigned int* XHb32 = (unsigned int*)(ws + ((size_t)41 << 20));

    hipMemsetAsync(pk, 0, (size_t)512 << 10, stream);
    k_detect<<<1, 256, 0, stream>>>((const unsigned short*)X, ei, flags);

    PackArgs pa;
    pa.Wx[0]=d_in[5];  pa.bx[0]=d_in[6];  pa.Wh[0]=d_in[7];  pa.bh[0]=d_in[8];
    pa.Wx[1]=d_in[9];  pa.bx[1]=d_in[10]; pa.Wh[1]=d_in[11]; pa.bh[1]=d_in[12];
    pa.Wx[2]=d_in[13]; pa.bx[2]=d_in[14]; pa.Wh[2]=d_in[15]; pa.bh[2]=d_in[16];
    pa.Wx[3]=d_in[17]; pa.bx[3]=d_in[18]; pa.Wh[3]=d_in[19]; pa.bh[3]=d_in[20];

    int nbC = (E + 2047)/2048;        // cnt blocks (8 edges/thread)
    int nbT = (N*32 + 255)/256;       // tobf blocks (16B/lane)
    k_fused1<<<nbC + nbT + 512, 256, 0, stream>>>(X, H, (uint4*)XHb32, ei, ew,
                                                  pk, off, pa, Bp, bias,
                                                  flags, nbC, nbT, E, N);

    int nbA = (N + 255)/256;
    k_scanA<<<nbA, 256, 0, stream>>>(pk, bsum, N);
    k_scanB<<<1, 256, 0, stream>>>(bsum, bsumoff, nbA);
    k_scanC<<<nbA, 256, 0, stream>>>(pk, bsumoff, rowstart, dis, N);

    k_scatter<<<(E + 1023)/1024, 256, 0, stream>>>(ei, ew, rowstart, off, recs, flags, E, N);
    k_gather<<<(N*64 + 255)/256, 256, 0, stream>>>(recs, rowstart, dis,
                                                   (const uint4*)XHb32,
                                                   (uint4*)AXH32, N);

    EpiArgs ea;
    ea.C   = C;
    ea.wci = d_in[21];
    ea.wcf = d_in[22];
    ea.wco = d_in[23];
    ea.bi  = d_in[24];
    ea.bff = d_in[25];
    ea.bc  = d_in[26];
    ea.bo  = d_in[27];
    k_gemm<<<(N + 31)/32, 256, 0, stream>>>((const unsigned short*)AXH32, Bp, bias,
                                            ea, d_out, flags, N);
}